// Round 4
// baseline (386.001 us; speedup 1.0000x reference)
//
#include <hip/hip_runtime.h>
#include <hip/hip_bf16.h>
#include <math.h>

#define Bb 16
#define Cc 512
#define Nn 2048

typedef unsigned short u16;
typedef __attribute__((ext_vector_type(8))) short bf16x8;
typedef __attribute__((ext_vector_type(4))) float f32x4;

typedef __attribute__((address_space(3))) unsigned as3_u32;
typedef __attribute__((address_space(1))) const unsigned as1_u32;

__device__ __forceinline__ float b2f(u16 u){ unsigned x = ((unsigned)u) << 16; return __builtin_bit_cast(float, x); }
__device__ __forceinline__ u16 f2b(float f){
  unsigned x = __builtin_bit_cast(unsigned, f);
  x += 0x7fffu + ((x >> 16) & 1u);
  return (u16)(x >> 16);
}

// async global -> LDS, 16B per lane; LDS dest is wave-uniform base + lane*16.
__device__ __forceinline__ void gload16(const u16* g, u16* l){
  __builtin_amdgcn_global_load_lds((as1_u32*)(uintptr_t)(const void*)g,
                                   (as3_u32*)(uintptr_t)(void*)l, 16, 0, 0);
}

#define BAR() do{ __builtin_amdgcn_s_barrier(); asm volatile("" ::: "memory"); }while(0)
#define WAITV8() asm volatile("s_waitcnt vmcnt(8)" ::: "memory")
#define WAITV4() asm volatile("s_waitcnt vmcnt(4)" ::: "memory")
#define WAITV0() asm volatile("s_waitcnt vmcnt(0)" ::: "memory")

// ---------------- weight f32 -> bf16 convert ----------------
__global__ __launch_bounds__(256) void k_cvt(const float* __restrict__ s0, const float* __restrict__ s1,
                                             const float* __restrict__ s2,
                                             u16* __restrict__ d0, u16* __restrict__ d1, u16* __restrict__ d2){
  const float* s = (blockIdx.z == 0) ? s0 : (blockIdx.z == 1) ? s1 : s2;
  u16* d = (blockIdx.z == 0) ? d0 : (blockIdx.z == 1) ? d1 : d2;
  int i = blockIdx.x * 256 + threadIdx.x;
  float4 v = ((const float4*)s)[i];
  ushort4 o; o.x = f2b(v.x); o.y = f2b(v.y); o.z = f2b(v.z); o.w = f2b(v.w);
  ((ushort4*)d)[i] = o;
}

// ---------------- GroupNorm -> h[c][n] (bf16) ----------------
__global__ __launch_bounds__(256) void k_gn(const float* __restrict__ x,
                                            const float* __restrict__ gamma,
                                            const float* __restrict__ beta,
                                            u16* __restrict__ h){
  int bid = blockIdx.x;
  int b = bid >> 5, g = bid & 31;
  const float4* xv = (const float4*)(x + ((size_t)b * Cc + g * 16) * Nn);
  u16* hp = h + ((size_t)b * Cc + g * 16) * Nn;
  int t = threadIdx.x;
  float s = 0.f, ss = 0.f;
#pragma unroll 4
  for (int it = 0; it < 32; ++it){
    float4 v = xv[it * 256 + t];
    s  += v.x + v.y + v.z + v.w;
    ss += v.x * v.x + v.y * v.y + v.z * v.z + v.w * v.w;
  }
#pragma unroll
  for (int o = 32; o >= 1; o >>= 1){ s += __shfl_xor(s, o); ss += __shfl_xor(ss, o); }
  __shared__ float rs[4], rss[4];
  int w = t >> 6;
  if ((t & 63) == 0){ rs[w] = s; rss[w] = ss; }
  __syncthreads();
  s  = rs[0] + rs[1] + rs[2] + rs[3];
  ss = rss[0] + rss[1] + rss[2] + rss[3];
  float mean = s * (1.f / 32768.f);
  float var  = ss * (1.f / 32768.f) - mean * mean;
  float inv  = rsqrtf(var + 1e-6f);
#pragma unroll 4
  for (int it = 0; it < 32; ++it){
    int idx = it * 256 + t;
    float4 u = xv[idx];
    int ch = g * 16 + (idx >> 9);
    float ga = gamma[ch] * inv, be = beta[ch];
    ushort4 o;
    o.x = f2b((u.x - mean) * ga + be);
    o.y = f2b((u.y - mean) * ga + be);
    o.z = f2b((u.z - mean) * ga + be);
    o.w = f2b((u.w - mean) * ga + be);
    ((ushort4*)hp)[idx] = o;
  }
}

// ---------------- transpose h[c][n] -> h_t[n][c] ----------------
__global__ __launch_bounds__(256) void k_tr(const u16* __restrict__ h, u16* __restrict__ ht){
  __shared__ u16 lds[64 * 65];
  int b = blockIdx.z;
  int n0 = blockIdx.x * 64, c0 = blockIdx.y * 64;
  const u16* src = h + (size_t)b * Cc * Nn;
  u16* dst = ht + (size_t)b * Nn * Cc;
  int t = threadIdx.x;
  int jc = (t & 7) << 3;
  int r  = t >> 3;
#pragma unroll
  for (int it = 0; it < 2; ++it){
    int rr = r + it * 32;
    uint4 vv = *(const uint4*)(src + (size_t)(c0 + rr) * Nn + n0 + jc);
    u16* pv = (u16*)&vv;
#pragma unroll
    for (int e = 0; e < 8; ++e) lds[(jc + e) * 65 + rr] = pv[e];
  }
  __syncthreads();
#pragma unroll
  for (int it = 0; it < 2; ++it){
    int rn = r + it * 32;
    u16 tmp[8];
#pragma unroll
    for (int e = 0; e < 8; ++e) tmp[e] = lds[rn * 65 + jc + e];
    *(uint4*)(dst + (size_t)(n0 + rn) * Cc + c0 + jc) = *(const uint4*)tmp;
  }
}

// =====================================================================
// 256x256 / BK=32 / 8-wave GEMM core, 4-slot rotating LDS (128 KB),
// prefetch distance 3 tiles, counted vmcnt(8), ONE barrier per K-tile.
// C[256][256] = A[256 rows][K] * B[256 rows][K]^T (both [row][k]).
// XOR swizzle chunk^=(row>>1)&3 via pre-swizzled global source (linear LDS dst).
// MFMA operand order swapped: acc[i][j] = mfma(b[j], a[i]) so that
// lane holds 4 CONSECUTIVE output cols (reg dim) -> packed 8B/16B stores.
// =====================================================================
#define SLOT_U16 16384

__device__ __forceinline__ void gemm256(const u16* __restrict__ A, int lda,
                                        const u16* __restrict__ B, int ldb, int K,
                                        u16* __restrict__ lds, f32x4 (&acc)[8][4]){
  const int tid = threadIdx.x;
  const int w = tid >> 6, lane = tid & 63;
  const int lr = lane & 15, lk = lane >> 4;
  const int wr = w >> 2, wc = w & 3;

  // fragment read offsets (u16 units; row stride = 32 u16 = 64 B)
  const int swzc = lk ^ ((lr >> 1) & 3);
  const int aoff = (wr * 128 + lr) * 32 + 8 * swzc;
  const int boff = 8192 + (wc * 64 + lr) * 32 + 8 * swzc;

  // staging: thread covers block-linear lane-slots idx0, idx1 (0..1023)
  const int idx0 = w * 128 + lane;
  const int idx1 = idx0 + 64;
  const int r0s = idx0 >> 2, r1s = idx1 >> 2;
  const int c0 = (idx0 & 3) ^ ((r0s >> 1) & 3);
  const int c1 = (idx1 & 3) ^ ((r1s >> 1) & 3);
  const u16* gA0 = A + (size_t)r0s * lda + 8 * c0;
  const u16* gA1 = A + (size_t)r1s * lda + 8 * c1;
  const u16* gB0 = B + (size_t)r0s * ldb + 8 * c0;
  const u16* gB1 = B + (size_t)r1s * ldb + 8 * c1;
  const int dst0 = w * 1024;          // (w*128)*8 u16
  const int dst1 = dst0 + 512;

#pragma unroll
  for (int i = 0; i < 8; ++i)
#pragma unroll
    for (int j = 0; j < 4; ++j){ f32x4 z = {0.f,0.f,0.f,0.f}; acc[i][j] = z; }

  const int NT = K >> 5;

  // prologue: stage tiles 0,1,2 into slots 0,1,2 (12 loads/thread)
#pragma unroll
  for (int t = 0; t < 3; ++t){
    u16* sl = lds + t * SLOT_U16;
    const int kk = t << 5;
    gload16(gA0 + kk, sl + dst0);        gload16(gA1 + kk, sl + dst1);
    gload16(gB0 + kk, sl + 8192 + dst0); gload16(gB1 + kk, sl + 8192 + dst1);
  }
  WAITV8();   // tile 0 landed; tiles 1,2 in flight
  BAR();

#pragma unroll 1
  for (int T = 0; T < NT; ++T){
    const u16* Asl = lds + (T & 3) * SLOT_U16;

    // prefetch tile T+3 into slot (T+3)&3 (its previous tile T-1 fully read)
    if (T + 3 < NT){
      u16* stl = lds + ((T + 3) & 3) * SLOT_U16;
      const int kk = (T + 3) << 5;
      gload16(gA0 + kk, stl + dst0);        gload16(gA1 + kk, stl + dst1);
      gload16(gB0 + kk, stl + 8192 + dst0); gload16(gB1 + kk, stl + 8192 + dst1);
    }

    bf16x8 a[8], b[4];
#pragma unroll
    for (int i = 0; i < 8; ++i) a[i] = *(const bf16x8*)(Asl + aoff + i * 512);
#pragma unroll
    for (int j = 0; j < 4; ++j) b[j] = *(const bf16x8*)(Asl + boff + j * 512);

    __builtin_amdgcn_s_setprio(1);
#pragma unroll
    for (int i = 0; i < 8; ++i)
#pragma unroll
      for (int j = 0; j < 4; ++j)
        acc[i][j] = __builtin_amdgcn_mfma_f32_16x16x32_bf16(b[j], a[i], acc[i][j], 0, 0, 0);
    __builtin_amdgcn_s_setprio(0);

    // drain so tile T+1 is fully landed before anyone reads it next iter
    if (T + 3 < NT)      { WAITV8(); }
    else if (T + 2 < NT) { WAITV4(); }
    else if (T + 1 < NT) { WAITV0(); }
    BAR();
  }
}

// epilogue coords: lane holds row = base + i*16 + lr, cols = base + j*16 + g4 + 0..3
#define EPI_COORDS \
  int lane = threadIdx.x & 63, w = threadIdx.x >> 6; \
  int wr = w >> 2, wc = w & 3; \
  int lr = lane & 15; \
  int g4 = (lane >> 4) << 2;

// ---------------- q_t / k_t: [n][co] ----------------
__global__ __launch_bounds__(512, 2) void k_qkt(const u16* __restrict__ ht,
                                                const u16* __restrict__ wqb, const u16* __restrict__ wkb,
                                                const float* __restrict__ bq, const float* __restrict__ bk,
                                                u16* __restrict__ qt, u16* __restrict__ kt){
  __shared__ u16 lds[4 * SLOT_U16];
  int z = blockIdx.z, b = z >> 1, p = z & 1;
  int m0 = blockIdx.x * 256, n0 = blockIdx.y * 256;
  const u16* A = ht + (size_t)b * Nn * Cc + (size_t)m0 * Cc;
  const u16* B = (p ? wkb : wqb) + (size_t)n0 * Cc;
  const float* bias = p ? bk : bq;
  u16* out = (p ? kt : qt) + (size_t)b * Nn * Cc;
  f32x4 acc[8][4];
  gemm256(A, Cc, B, Cc, Cc, lds, acc);
  EPI_COORDS
#pragma unroll
  for (int i = 0; i < 8; ++i){
    int row = m0 + wr * 128 + i * 16 + lr;
#pragma unroll
    for (int j = 0; j < 4; ++j){
      int coln = n0 + wc * 64 + j * 16 + g4;
      float4 bi = *(const float4*)(bias + coln);
      ushort4 o;
      o.x = f2b(acc[i][j][0] + bi.x);
      o.y = f2b(acc[i][j][1] + bi.y);
      o.z = f2b(acc[i][j][2] + bi.z);
      o.w = f2b(acc[i][j][3] + bi.w);
      *(ushort4*)(out + (size_t)row * Cc + coln) = o;
    }
  }
}

// ---------------- v: [co][n] ----------------
__global__ __launch_bounds__(512, 2) void k_vproj(const u16* __restrict__ wvb, const u16* __restrict__ ht,
                                                  const float* __restrict__ bv, u16* __restrict__ v){
  __shared__ u16 lds[4 * SLOT_U16];
  int b = blockIdx.z;
  int m0 = blockIdx.x * 256, n0 = blockIdx.y * 256;
  const u16* A = wvb + (size_t)m0 * Cc;
  const u16* B = ht + (size_t)b * Nn * Cc + (size_t)n0 * Cc;
  u16* out = v + (size_t)b * Cc * Nn;
  f32x4 acc[8][4];
  gemm256(A, Cc, B, Cc, Cc, lds, acc);
  EPI_COORDS
#pragma unroll
  for (int i = 0; i < 8; ++i){
    int row = m0 + wr * 128 + i * 16 + lr;
    float bi = bv[row];
#pragma unroll
    for (int j = 0; j < 4; ++j){
      int coln = n0 + wc * 64 + j * 16 + g4;
      ushort4 o;
      o.x = f2b(acc[i][j][0] + bi);
      o.y = f2b(acc[i][j][1] + bi);
      o.z = f2b(acc[i][j][2] + bi);
      o.w = f2b(acc[i][j][3] + bi);
      *(ushort4*)(out + (size_t)row * Nn + coln) = o;
    }
  }
}

// ---------------- scores: P[nq][m] = scale * q_t k_t^T (XCD-chunked 1D grid) ----------------
__global__ __launch_bounds__(512, 2) void k_scores(const u16* __restrict__ qt, const u16* __restrict__ kt,
                                                   u16* __restrict__ p){
  __shared__ u16 lds[4 * SLOT_U16];
  int bid = blockIdx.x;                       // 1024 blocks, 1024%8==0
  int swz = (bid & 7) * 128 + (bid >> 3);
  int b = swz >> 6, rem = swz & 63;
  int m0 = (rem & 7) * 256, n0 = (rem >> 3) * 256;
  const u16* A = qt + (size_t)b * Nn * Cc + (size_t)m0 * Cc;
  const u16* B = kt + (size_t)b * Nn * Cc + (size_t)n0 * Cc;
  u16* pb = p + (size_t)b * Nn * Nn;
  f32x4 acc[8][4];
  gemm256(A, Cc, B, Cc, Cc, lds, acc);
  const float scale = 0.044194173824159216f;
  EPI_COORDS
#pragma unroll
  for (int i = 0; i < 8; ++i){
    int row = m0 + wr * 128 + i * 16 + lr;
#pragma unroll
    for (int j = 0; j < 4; ++j){
      int coln = n0 + wc * 64 + j * 16 + g4;
      ushort4 o;
      o.x = f2b(acc[i][j][0] * scale);
      o.y = f2b(acc[i][j][1] * scale);
      o.z = f2b(acc[i][j][2] * scale);
      o.w = f2b(acc[i][j][3] * scale);
      *(ushort4*)(pb + (size_t)row * Nn + coln) = o;
    }
  }
}

// ---------------- row softmax in place over P ----------------
__global__ __launch_bounds__(256) void k_softmax(u16* __restrict__ p){
  size_t r = blockIdx.x;
  u16* row = p + r * (size_t)Nn;
  int t = threadIdx.x;
  uint4 raw = ((uint4*)row)[t];
  u16* u = (u16*)&raw;
  float vals[8];
  float m = -1e30f;
#pragma unroll
  for (int e = 0; e < 8; ++e){ vals[e] = b2f(u[e]); m = fmaxf(m, vals[e]); }
#pragma unroll
  for (int o = 32; o >= 1; o >>= 1) m = fmaxf(m, __shfl_xor(m, o));
  __shared__ float sm[4], ssum[4];
  int w = t >> 6;
  if ((t & 63) == 0) sm[w] = m;
  __syncthreads();
  m = fmaxf(fmaxf(sm[0], sm[1]), fmaxf(sm[2], sm[3]));
  float s = 0.f;
#pragma unroll
  for (int e = 0; e < 8; ++e){ vals[e] = __expf(vals[e] - m); s += vals[e]; }
#pragma unroll
  for (int o = 32; o >= 1; o >>= 1) s += __shfl_xor(s, o);
  if ((t & 63) == 0) ssum[w] = s;
  __syncthreads();
  s = ssum[0] + ssum[1] + ssum[2] + ssum[3];
  float inv = 1.f / s;
#pragma unroll
  for (int e = 0; e < 8; ++e) u[e] = f2b(vals[e] * inv);
  ((uint4*)row)[t] = raw;
}

// ---------------- PV: ao_t[nq][c] = P[nq][m] * v[c][m]^T (XCD-chunked 1D grid) ----------------
__global__ __launch_bounds__(512, 2) void k_pv(const u16* __restrict__ p, const u16* __restrict__ v,
                                               u16* __restrict__ aot){
  __shared__ u16 lds[4 * SLOT_U16];
  int bid = blockIdx.x;                       // 256 blocks
  int swz = (bid & 7) * 32 + (bid >> 3);
  int b = swz >> 4, rem = swz & 15;
  int m0 = (rem & 7) * 256, n0 = (rem >> 3) * 256;
  const u16* A = p + (size_t)b * Nn * Nn + (size_t)m0 * Nn;
  const u16* B = v + (size_t)b * Cc * Nn + (size_t)n0 * Nn;
  u16* out = aot + (size_t)b * Nn * Cc;
  f32x4 acc[8][4];
  gemm256(A, Nn, B, Nn, Nn, lds, acc);
  EPI_COORDS
#pragma unroll
  for (int i = 0; i < 8; ++i){
    int row = m0 + wr * 128 + i * 16 + lr;
#pragma unroll
    for (int j = 0; j < 4; ++j){
      int coln = n0 + wc * 64 + j * 16 + g4;
      ushort4 o;
      o.x = f2b(acc[i][j][0]);
      o.y = f2b(acc[i][j][1]);
      o.z = f2b(acc[i][j][2]);
      o.w = f2b(acc[i][j][3]);
      *(ushort4*)(out + (size_t)row * Cc + coln) = o;
    }
  }
}

// ---------------- proj + residual (fp32 out, float4 stores) ----------------
__global__ __launch_bounds__(512, 2) void k_proj(const u16* __restrict__ wob, const u16* __restrict__ aot,
                                                 const float* __restrict__ bo, const float* __restrict__ x,
                                                 float* __restrict__ out){
  __shared__ u16 lds[4 * SLOT_U16];
  int b = blockIdx.z;
  int m0 = blockIdx.x * 256, n0 = blockIdx.y * 256;
  const u16* A = wob + (size_t)m0 * Cc;
  const u16* B = aot + (size_t)b * Nn * Cc + (size_t)n0 * Cc;
  f32x4 acc[8][4];
  gemm256(A, Cc, B, Cc, Cc, lds, acc);
  size_t base = (size_t)b * Cc * Nn;
  EPI_COORDS
#pragma unroll
  for (int i = 0; i < 8; ++i){
    int row = m0 + wr * 128 + i * 16 + lr;
    float bi = bo[row];
#pragma unroll
    for (int j = 0; j < 4; ++j){
      int coln = n0 + wc * 64 + j * 16 + g4;
      size_t idx = base + (size_t)row * Nn + coln;
      float4 xv = *(const float4*)(x + idx);
      float4 o;
      o.x = xv.x + bi + acc[i][j][0];
      o.y = xv.y + bi + acc[i][j][1];
      o.z = xv.z + bi + acc[i][j][2];
      o.w = xv.w + bi + acc[i][j][3];
      *(float4*)(out + idx) = o;
    }
  }
}

extern "C" void kernel_launch(void* const* d_in, const int* in_sizes, int n_in,
                              void* d_out, int out_size, void* d_ws, size_t ws_size,
                              hipStream_t stream){
  const float* x     = (const float*)d_in[0];
  const float* gamma = (const float*)d_in[1];
  const float* beta  = (const float*)d_in[2];
  const float* wq = (const float*)d_in[3];
  const float* bq = (const float*)d_in[4];
  const float* wk = (const float*)d_in[5];
  const float* bk = (const float*)d_in[6];
  const float* wv = (const float*)d_in[7];
  const float* bv = (const float*)d_in[8];
  const float* wo = (const float*)d_in[9];
  const float* bo = (const float*)d_in[10];
  float* out = (float*)d_out;

  char* ws = (char*)d_ws;
  const size_t MB = 1048576ull;
  u16* ht  = (u16*)(ws);             // 32MB: h_t[n][c]; reused as ao_t later
  u16* qt  = (u16*)(ws + 32 * MB);   // 32MB; reused as wo_bf after scores
  u16* kt  = (u16*)(ws + 64 * MB);   // 32MB
  u16* v   = (u16*)(ws + 96 * MB);   // 32MB: v[c][n]
  u16* P   = (u16*)(ws + 128 * MB);  // 128MB
  u16* wqb = P;                      // transients (dead before P written)
  u16* wkb = P + 262144;
  u16* wvb = P + 524288;
  u16* h   = (u16*)(ws + 130 * MB);  // 32MB: h[c][n]
  u16* wob = qt;
  u16* aot = ht;

  k_cvt<<<dim3(256, 1, 3), 256, 0, stream>>>(wq, wk, wv, wqb, wkb, wvb);
  k_gn<<<dim3(512), 256, 0, stream>>>(x, gamma, beta, h);
  k_tr<<<dim3(32, 8, 16), 256, 0, stream>>>(h, ht);
  k_qkt<<<dim3(8, 2, 32), 512, 0, stream>>>(ht, wqb, wkb, bq, bk, qt, kt);
  k_vproj<<<dim3(2, 8, 16), 512, 0, stream>>>(wvb, ht, bv, v);
  k_scores<<<dim3(1024), 512, 0, stream>>>(qt, kt, P);
  k_cvt<<<dim3(256, 1, 1), 256, 0, stream>>>(wo, wo, wo, wob, wob, wob);
  k_softmax<<<dim3(32768), 256, 0, stream>>>(P);
  k_pv<<<dim3(256), 512, 0, stream>>>(P, v, aot);
  k_proj<<<dim3(2, 8, 16), 512, 0, stream>>>(wob, aot, bo, x, out);
}